// Round 2
// baseline (130.332 us; speedup 1.0000x reference)
//
#include <hip/hip_runtime.h>

// CompletePatchReadout: grouped GEMM (128 patches, M=32 K=1536 N=768) + bias + row scatter.
// Memory-bound on W (604 MB fp32, read once). bf16 MFMA, W loaded direct-to-register.
// (Resubmit: round-1 bench died on UnresponsiveContainer before running.)

constexpr int BATCH  = 32;
constexpr int T      = 12;
constexpr int P      = 128;
constexpr int F      = 128;
constexpr int K      = T * F;        // 1536
constexpr int N      = 768;          // 64 nodes * 12 horizon
constexpr int NPP    = 64;           // nodes per patch
constexpr int H      = 12;
constexpr int NNODES = P * NPP;      // 8192
constexpr int BN     = 128;          // N-tile per block
constexpr int BK     = 64;           // K-step
constexpr int NT     = N / BN;       // 6 n-tiles per patch

typedef __attribute__((ext_vector_type(8))) short  bf16x8;
typedef __attribute__((ext_vector_type(4))) float  f32x4;

__device__ inline short f2bf(float f) {            // fp32 -> bf16 round-to-nearest-even
    unsigned u = __float_as_uint(f);
    u += 0x7fffu + ((u >> 16) & 1u);
    return (short)(u >> 16);
}

__global__ __launch_bounds__(256, 2)
void patch_readout_kernel(const float* __restrict__ x,
                          const float* __restrict__ W,
                          const float* __restrict__ bias,
                          const int*   __restrict__ map,
                          float*       __restrict__ out)
{
    // A (x) tile: 32 rows x 64 bf16, double-buffered, XOR-swizzled on 16B slots.
    __shared__ short As[2][32 * 64];

    const int p    = blockIdx.y;
    const int n0   = blockIdx.x * BN;
    const int tid  = threadIdx.x;
    const int lane = tid & 63;
    const int wv   = tid >> 6;        // wave 0..3 -> 32-col slice
    const int r    = lane & 15;
    const int c    = lane >> 4;       // k-chunk 0..3

    // A staging assignment: thread -> (row sm 0..31, k-octet skq 0..7)
    const int sm  = tid >> 3;
    const int skq = tid & 7;
    const float* xrow = x + (size_t)sm * T * P * F + (size_t)p * F;
    const int abyte = (sm * 128 + skq * 16) ^ ((sm & 7) << 4);

    // W per-lane base: fragment layout lane l -> col = l&15, k = 8*(l>>4) + j
    const float* wbase = W + (size_t)p * K * N + (size_t)(8 * c) * N + (n0 + wv * 32 + r);

    f32x4 acc[2][2] = {};             // [mi][ni], each 16x16 C fragment
    char* asbase = (char*)&As[0][0];

    int buf = 0;
    for (int k0 = 0; k0 < K; k0 += BK, buf ^= 1) {
        // ---- stage A tile fp32 -> bf16 into LDS (coalesced 32B/thread) ----
        const int t  = k0 >> 7;       // F == 128
        const int fb = k0 & 127;
        const f32x4* xp = (const f32x4*)(xrow + (size_t)t * P * F + fb + skq * 8);
        f32x4 v0 = xp[0];
        f32x4 v1 = xp[1];
        bf16x8 av;
        av[0] = f2bf(v0.x); av[1] = f2bf(v0.y); av[2] = f2bf(v0.z); av[3] = f2bf(v0.w);
        av[4] = f2bf(v1.x); av[5] = f2bf(v1.y); av[6] = f2bf(v1.z); av[7] = f2bf(v1.w);
        *(bf16x8*)(asbase + buf * 4096 + abyte) = av;

        // ---- B fragments straight from global (W has zero reuse; skip LDS) ----
        bf16x8 bfr[2][2];             // [kc][ni]
        #pragma unroll
        for (int kc = 0; kc < 2; ++kc) {
            #pragma unroll
            for (int ni = 0; ni < 2; ++ni) {
                const float* wp = wbase + (size_t)(k0 + kc * 32) * N + ni * 16;
                #pragma unroll
                for (int j = 0; j < 8; ++j)
                    bfr[kc][ni][j] = f2bf(wp[(size_t)j * N]);
            }
        }

        __syncthreads();              // A tile visible; other buffer free for next iter

        // ---- A fragments from LDS (ds_read_b128, swizzled) ----
        bf16x8 afr[2][2];             // [mi][kc]
        #pragma unroll
        for (int mi = 0; mi < 2; ++mi) {
            #pragma unroll
            for (int kc = 0; kc < 2; ++kc) {
                int m    = mi * 16 + r;
                int byte = (m * 128 + kc * 64 + c * 16) ^ ((m & 7) << 4);
                afr[mi][kc] = *(const bf16x8*)(asbase + buf * 4096 + byte);
            }
        }

        // ---- MFMA: acc += A * B over the two K=32 sub-steps ----
        #pragma unroll
        for (int mi = 0; mi < 2; ++mi)
            #pragma unroll
            for (int ni = 0; ni < 2; ++ni)
                #pragma unroll
                for (int kc = 0; kc < 2; ++kc)
                    acc[mi][ni] = __builtin_amdgcn_mfma_f32_16x16x32_bf16(
                        afr[mi][kc], bfr[kc][ni], acc[mi][ni], 0, 0, 0);
    }

    // ---- epilogue: bias + permutation scatter ----
    #pragma unroll
    for (int ni = 0; ni < 2; ++ni) {
        const int col = n0 + wv * 32 + ni * 16 + r;   // output col o in [0,768)
        const int nl  = col / H;                      // patch-local node
        const int h   = col - nl * H;                 // horizon
        const int g   = map[p * NPP + nl];            // global node
        const float bv = bias[p * N + col];
        #pragma unroll
        for (int mi = 0; mi < 2; ++mi) {
            #pragma unroll
            for (int i = 0; i < 4; ++i) {
                const int b = mi * 16 + c * 4 + i;    // batch row (C/D layout, verified)
                out[((size_t)b * NNODES + g) * H + h] = acc[mi][ni][i] + bv;
            }
        }
    }
}

extern "C" void kernel_launch(void* const* d_in, const int* in_sizes, int n_in,
                              void* d_out, int out_size, void* d_ws, size_t ws_size,
                              hipStream_t stream) {
    const float* x    = (const float*)d_in[0];
    const float* W    = (const float*)d_in[1];
    const float* bias = (const float*)d_in[2];
    const int*   map  = (const int*)d_in[3];
    float*       out  = (float*)d_out;

    dim3 grid(NT, P);   // (6, 128) = 768 blocks
    dim3 block(256);
    patch_readout_kernel<<<grid, block, 0, stream>>>(x, W, bias, map, out);
}